// Round 11
// baseline (208.968 us; speedup 1.0000x reference)
//
#include <hip/hip_runtime.h>
#include <hip/hip_bf16.h>

typedef __attribute__((ext_vector_type(8)))  short        short8;
typedef __attribute__((ext_vector_type(4)))  float        f32x4;
typedef __attribute__((ext_vector_type(16))) float        f32x16;
typedef __attribute__((ext_vector_type(4)))  unsigned int uint4v;
typedef __attribute__((ext_vector_type(2)))  unsigned int uint2v;

#define MFMA16x16(a,b,c) __builtin_amdgcn_mfma_f32_16x16x32_bf16((a),(b),(c),0,0,0)
#define MFMA32x32(a,b,c) __builtin_amdgcn_mfma_f32_32x32x16_bf16((a),(b),(c),0,0,0)

__device__ __forceinline__ unsigned cvt_pk_bf16(float lo, float hi){
  unsigned r;
  asm("v_cvt_pk_bf16_f32 %0, %1, %2" : "=v"(r) : "v"(lo), "v"(hi));
  return r;
}
__device__ __forceinline__ unsigned short bf16_1(float v){
  return (unsigned short)(cvt_pk_bf16(v, v) & 0xffffu);
}
__device__ __forceinline__ float bf2f(unsigned short u){
  union { unsigned u; float f; } cv; cv.u = ((unsigned)u) << 16; return cv.f;
}
__device__ __forceinline__ void gll16(const void* src, void* dst){
  __builtin_amdgcn_global_load_lds((const __attribute__((address_space(1))) unsigned int*)src,
                                   (__attribute__((address_space(3))) unsigned int*)dst, 16, 0, 0);
}
__device__ __forceinline__ f32x16 zero16(){ f32x16 v; 
#pragma unroll
  for (int i=0;i<16;i++) v[i]=0.0f; return v; }
__device__ __forceinline__ f32x4 zero4(){ f32x4 v;
#pragma unroll
  for (int i=0;i<4;i++) v[i]=0.0f; return v; }

// 2^x for tiny |x|: 3 FMAs, no guard sequence.
__device__ __forceinline__ float exp2_tiny(float x){
  const float C1 = 0.6931471805599453f;
  const float C2 = 0.2402265069591007f;
  const float C3 = 0.0555041086648216f;
  return fmaf(x, fmaf(x, fmaf(x, C3, C2), C1), 1.0f);
}

// pi: self-inverse bit swap of bits 2 and 3
__device__ __forceinline__ int kperm(int i){
  return (i & ~12) | ((i & 4) << 1) | ((i & 8) >> 1);
}

// ---------------------------------------------------------------- generic fp32 -> bf16 (grid*256*8 elems)
__global__ void lt_conv(const float* __restrict__ src, unsigned short* __restrict__ dst){
  size_t i = ((size_t)blockIdx.x * 256 + threadIdx.x) * 8;
  f32x4 a = *(const f32x4*)(src + i);
  f32x4 b = *(const f32x4*)(src + i + 4);
  uint4v o;
  o.x = cvt_pk_bf16(a.x, a.y); o.y = cvt_pk_bf16(a.z, a.w);
  o.z = cvt_pk_bf16(b.x, b.y); o.w = cvt_pk_bf16(b.z, b.w);
  *(uint4v*)(dst + i) = o;
}

// ---------------------------------------------------------------- shared 128x128 MFMA GEMM body (BK=64, 8 waves)
// Used by the small GEMMs (qproj, out-proj). atile/btile bf16 [128 x 512].
__device__ __forceinline__ void gemm128_body(const unsigned short* __restrict__ atile,
                                             const unsigned short* __restrict__ btile,
                                             char* smem, int tid, f32x4 acc[4][2]){
  unsigned short* A0 = (unsigned short*)smem;            // [2][128][64]
  unsigned short* B0 = (unsigned short*)(smem + 32768);
  int l = tid & 63; int w = tid >> 6;
  int wm = w >> 2, wn = w & 3;
  int l15 = l & 15, l4 = l >> 4;

#pragma unroll
  for (int mi=0;mi<4;mi++)
#pragma unroll
    for (int ni=0;ni<2;ni++) acc[mi][ni] = zero4();

  int srow = (w*2)*8 + (l>>3);
  int gcp0 = (l&7) ^ (srow & 7);
  int srow1 = srow + 8;
  int gcp1 = (l&7) ^ (srow1 & 7);
  const unsigned short* asrc0 = atile + (size_t)srow *512 + gcp0*8;
  const unsigned short* asrc1 = atile + (size_t)srow1*512 + gcp1*8;
  const unsigned short* bsrc0 = btile + (size_t)srow *512 + gcp0*8;
  const unsigned short* bsrc1 = btile + (size_t)srow1*512 + gcp1*8;
  int ldsL = (w*2)*512;

  auto stage = [&](int buf, int k0){
    unsigned short* A = A0 + buf*8192;
    unsigned short* B = B0 + buf*8192;
    gll16(asrc0 + k0, A + ldsL);
    gll16(asrc1 + k0, A + ldsL + 512);
    gll16(bsrc0 + k0, B + ldsL);
    gll16(bsrc1 + k0, B + ldsL + 512);
  };

  stage(0, 0);
  __syncthreads();

#pragma unroll 2
  for (int t=0; t<8; t++){
    int cur = t & 1;
    if (t < 7) stage(cur^1, (t+1)*64);
    const unsigned short* A = A0 + cur*8192;
    const unsigned short* B = B0 + cur*8192;
#pragma unroll
    for (int ks=0; ks<2; ks++){
      short8 af[4], bfq[2];
#pragma unroll
      for (int mi=0;mi<4;mi++){
        int row = wm*64 + mi*16 + l15;
        int gc = ks*4 + l4;
        af[mi] = *(const short8*)(A + row*64 + ((gc ^ (row&7))<<3));
      }
#pragma unroll
      for (int ni=0;ni<2;ni++){
        int row = wn*32 + ni*16 + l15;
        int gc = ks*4 + l4;
        bfq[ni] = *(const short8*)(B + row*64 + ((gc ^ (row&7))<<3));
      }
#pragma unroll
      for (int mi=0;mi<4;mi++)
#pragma unroll
        for (int ni=0;ni<2;ni++)
          acc[mi][ni] = MFMA16x16(af[mi], bfq[ni], acc[mi][ni]);
    }
    __syncthreads();
  }
}

// ---------------------------------------------------------------- K2: KV projection GEMM (m97-replica shape)
// 128x128 tile, BK=64, 4 waves (2x2), wave tile 64x64 = acc[4][4] of 16x16 frags.
// 16 b128 reads -> 32 MFMA per wave-step (0.5 reads/MFMA), 16-row pattern = 2-way-free.
__global__ __launch_bounds__(256, 2) void lt_gemm_kv(const unsigned short* __restrict__ xbf,
                                                     const unsigned short* __restrict__ wkv,
                                                     const float* __restrict__ bias,
                                                     unsigned short* __restrict__ kbuf,
                                                     unsigned short* __restrict__ vtbuf){
  __shared__ char smem[65536];
  unsigned short* A0 = (unsigned short*)smem;            // [2][128][64]
  unsigned short* B0 = (unsigned short*)(smem + 32768);

  int bid = blockIdx.x;
  int xcd = bid & 7; int ii = bid >> 3;
  int m0 = xcd*64 + (ii>>3); int n0 = ii & 7;
  int tid = threadIdx.x; int l = tid & 63; int w = tid >> 6;   // w 0..3
  int wm = w >> 1, wn = w & 1;
  int l15 = l & 15, l4 = l >> 4;

  f32x4 acc[4][4];
#pragma unroll
  for (int mi=0;mi<4;mi++)
#pragma unroll
    for (int ni=0;ni<4;ni++) acc[mi][ni] = zero4();

  // staging: 4 chunks (8 rows x 64 k) per operand per wave
  const unsigned short* asrc[4];
  const unsigned short* bsrc[4];
  int ldsoff[4];
#pragma unroll
  for (int li=0; li<4; li++){
    int L = w*4 + li;
    int row = L*8 + (l>>3);
    int gcp = (l&7) ^ (row & 7);
    asrc[li] = xbf + (size_t)(m0*128 + row)*512 + gcp*8;
    bsrc[li] = wkv + (size_t)(n0*128 + row)*512 + gcp*8;
    ldsoff[li] = L*512;
  }

  auto stage = [&](int buf, int k0){
    unsigned short* A = A0 + buf*8192;
    unsigned short* B = B0 + buf*8192;
#pragma unroll
    for (int li=0; li<4; li++){
      gll16(asrc[li] + k0, A + ldsoff[li]);
      gll16(bsrc[li] + k0, B + ldsoff[li]);
    }
  };

  stage(0, 0);
  __syncthreads();

#pragma unroll 2
  for (int t=0; t<8; t++){
    int cur = t & 1;
    if (t < 7) stage(cur^1, (t+1)*64);
    const unsigned short* A = A0 + cur*8192;
    const unsigned short* B = B0 + cur*8192;
#pragma unroll
    for (int ks=0; ks<2; ks++){
      short8 af[4], bfq[4];
#pragma unroll
      for (int mi=0;mi<4;mi++){
        int row = wm*64 + mi*16 + l15;
        int gc = ks*4 + l4;
        af[mi] = *(const short8*)(A + row*64 + ((gc ^ (row&7))<<3));
      }
#pragma unroll
      for (int ni=0;ni<4;ni++){
        int row = wn*64 + ni*16 + l15;
        int gc = ks*4 + l4;
        bfq[ni] = *(const short8*)(B + row*64 + ((gc ^ (row&7))<<3));
      }
#pragma unroll
      for (int mi=0;mi<4;mi++)
#pragma unroll
        for (int ni=0;ni<4;ni++)
          acc[mi][ni] = MFMA16x16(af[mi], bfq[ni], acc[mi][ni]);
    }
    __syncthreads();
  }

  // ---- epilogue
  int fl = wn*64 + l15;
  float biasr[4];
#pragma unroll
  for (int ni=0;ni<4;ni++) biasr[ni] = bias[512 + n0*128 + fl + ni*16];

  if (n0 < 4){
    unsigned short* LK = (unsigned short*)smem;   // [128][136]
#pragma unroll
    for (int mi=0;mi<4;mi++)
#pragma unroll
      for (int ni=0;ni<4;ni++)
#pragma unroll
        for (int r=0;r<4;r++){
          int row = wm*64 + mi*16 + l4*4 + r;
          int f = fl + ni*16;
          LK[row*136 + f] = bf16_1(acc[mi][ni][r] + biasr[ni]);
        }
    __syncthreads();
    int gk0 = m0*128;
#pragma unroll
    for (int it=0; it<8; it++){
      int ci = it*256 + tid; int row = ci>>4, c = ci&15;
      uint4v d = *(const uint4v*)(LK + row*136 + c*8);
      int gk = gk0 + row; int b = gk>>13; int key = gk & 8191;
      int h = 2*n0 + (c>>3); int dh = (c&7)*8;
      *(uint4v*)(kbuf + ((size_t)(b*8+h)*8192 + key)*64 + dh) = d;
    }
  } else {
    unsigned short* LT = (unsigned short*)smem;   // [128 f][128 key], swizzled
#pragma unroll
    for (int mi=0;mi<4;mi++)
#pragma unroll
      for (int ni=0;ni<4;ni++)
#pragma unroll
        for (int r=0;r<4;r++){
          int key = wm*64 + mi*16 + l4*4 + r;
          int f = fl + ni*16;
          LT[f*128 + (key ^ ((f&7)<<2))] = bf16_1(acc[mi][ni][r] + biasr[ni]);
        }
    __syncthreads();
    int bb = m0 >> 6; int key0 = (m0 & 63)*128;
#pragma unroll
    for (int it=0; it<8; it++){
      int ci = it*256 + tid; int f = ci>>4, kb = ci&15;
      int sw = (f&7)<<2;
      uint2v lo = *(const uint2v*)(LT + f*128 + ((kb*8)   ^ sw));
      uint2v hi = *(const uint2v*)(LT + f*128 + ((kb*8+4) ^ sw));
      int vf = (n0-4)*128 + f; int hv = vf>>6, dh = vf&63;
      uint4v d; d.x = lo.x; d.y = lo.y; d.z = hi.x; d.w = hi.y;
      *(uint4v*)(vtbuf + ((size_t)((bb*8+hv)*64+dh))*8192 + key0 + kb*8) = d;
    }
  }
}

// ---------------------------------------------------------------- K1: q projection GEMM (8 blocks)
__global__ __launch_bounds__(512, 4) void lt_gemm_q(const unsigned short* __restrict__ qtbf,
                                                    const unsigned short* __restrict__ wqbf,
                                                    const float* __restrict__ bias,
                                                    unsigned short* __restrict__ qbuf){
  __shared__ char smem[65536];
  int bid = blockIdx.x;
  int m0 = bid >> 2, n0 = bid & 3;
  int tid = threadIdx.x; int l = tid & 63; int w = tid >> 6;
  int wm = w >> 2, wn = w & 3;
  int l15 = l & 15, l4 = l >> 4;

  f32x4 acc[4][2];
  gemm128_body(qtbf + (size_t)m0*128*512, wqbf + (size_t)n0*128*512, smem, tid, acc);

  const float SC = 0.18033688011112042f;   // log2(e)/sqrt(64)
  int fl = wn*32 + l15;
  float biasr[2];
#pragma unroll
  for (int ni=0;ni<2;ni++) biasr[ni] = bias[n0*128 + fl + ni*16];

  unsigned short* LK = (unsigned short*)smem;
#pragma unroll
  for (int mi=0;mi<4;mi++)
#pragma unroll
    for (int ni=0;ni<2;ni++)
#pragma unroll
      for (int r=0;r<4;r++){
        int row = wm*64 + mi*16 + l4*4 + r;
        int f = fl + ni*16;
        LK[row*136 + f] = bf16_1((acc[mi][ni][r] + biasr[ni]) * SC);
      }
  __syncthreads();
  size_t gbase = (size_t)m0*128*512 + n0*128;
#pragma unroll
  for (int it=0; it<4; it++){
    int ci = it*512 + tid; int row = ci>>4, c = ci&15;
    uint4v d = *(const uint4v*)(LK + row*136 + c*8);
    *(uint4v*)(qbuf + gbase + (size_t)row*512 + c*8) = d;
  }
}

// ---------------------------------------------------------------- K3: flash attention (unchanged)
__global__ __launch_bounds__(512, 4) void lt_attn(const unsigned short* __restrict__ kbuf,
                                                  const unsigned short* __restrict__ vtbuf,
                                                  const unsigned short* __restrict__ qbuf,
                                                  float* __restrict__ part,
                                                  float* __restrict__ zpart){
  __shared__ unsigned short lds[32768];
  int bid = blockIdx.x;
  int ksp = bid & 7, h = (bid>>3)&7, b = bid>>6;
  int tid = threadIdx.x; int l = tid & 63; int w = tid >> 6;
  int lq = l & 31, hl = l >> 5;
  int key_base = ksp*1024;

  short8 qf[4];
#pragma unroll
  for (int ks=0;ks<4;ks++){
    int t = 32*w + lq;
    qf[ks] = *(const short8*)(qbuf + (size_t)t*512 + h*64 + ks*16 + 8*hl);
  }

  f32x16 ctx[2]; ctx[0] = zero16(); ctx[1] = zero16();
  float zaccA = 0.0f, zaccB = 0.0f;

  int krow  = w*16 + (l>>3);
  int kgcp0 = (l&7) ^ (krow & 7);
  int krow1 = krow + 8;
  int kgcp1 = (l&7) ^ (krow1 & 7);
  const unsigned short* khead = kbuf + ((size_t)(b*8+h)*8192 + key_base)*64;
  const unsigned short* ksrc0 = khead + (size_t)kperm(krow )*64 + kgcp0*8;
  const unsigned short* ksrc1 = khead + (size_t)kperm(krow1)*64 + kgcp1*8;
  int vrow = w*8 + (l>>3);
  int vgcp = (l&7) ^ (vrow & 7);
  const unsigned short* vsrc = vtbuf + (size_t)((b*8+h)*64 + vrow)*8192 + key_base + vgcp*8;

  auto stage = [&](int buf, int kb){
    unsigned short* base = lds + buf*16384;
    size_t koff = (size_t)kb*128*64;
    gll16(ksrc0 + koff, base + (w*2  )*512);
    gll16(ksrc1 + koff, base + (w*2+1)*512);
    gll16(vsrc + kb*128,      base + 8192  + w*512);
    gll16(vsrc + kb*128 + 64, base + 12288 + w*512);
  };

  auto compute = [&](int buf, int sub){
    const unsigned short* baseK = lds + buf*16384 + sub*4096;
    const unsigned short* baseV = lds + buf*16384 + 8192 + sub*4096;
    f32x16 st[2];
    short8 kfk[4];
    __builtin_amdgcn_s_setprio(1);
#pragma unroll
    for (int kt=0;kt<2;kt++){
#pragma unroll
      for (int ks=0;ks<4;ks++){
        int row = kt*32 + lq;
        int gc = 2*ks + hl;
        kfk[ks] = *(const short8*)(baseK + row*64 + ((gc ^ (row&7))<<3));
      }
      st[kt] = zero16();
#pragma unroll
      for (int ks=0;ks<4;ks++)
        st[kt] = MFMA32x32(kfk[ks], qf[ks], st[kt]);
    }
    __builtin_amdgcn_s_setprio(0);
#pragma unroll
    for (int r=0;r<16;r++){
      float e0 = exp2_tiny(st[0][r]);
      float e1 = exp2_tiny(st[1][r]);
      st[0][r] = e0; zaccA += e0;
      st[1][r] = e1; zaccB += e1;
    }
    __builtin_amdgcn_s_setprio(1);
#pragma unroll
    for (int ks=0;ks<4;ks++){
      int kt = ks>>1, o = (ks&1)*8;
      int gc = 2*ks + hl;
      int row0 = lq, row1 = 32 + lq;
      short8 v0 = *(const short8*)(baseV + row0*64 + ((gc ^ (row0&7))<<3));
      short8 v1 = *(const short8*)(baseV + row1*64 + ((gc ^ (row1&7))<<3));
      uint4v pw;
      pw.x = cvt_pk_bf16(st[kt][o+0], st[kt][o+1]);
      pw.y = cvt_pk_bf16(st[kt][o+2], st[kt][o+3]);
      pw.z = cvt_pk_bf16(st[kt][o+4], st[kt][o+5]);
      pw.w = cvt_pk_bf16(st[kt][o+6], st[kt][o+7]);
      union { uint4v u; short8 s; } pc; pc.u = pw;
      ctx[0] = MFMA32x32(pc.s, v0, ctx[0]);
      ctx[1] = MFMA32x32(pc.s, v1, ctx[1]);
    }
    __builtin_amdgcn_s_setprio(0);
  };

  stage(0, 0);
  __syncthreads();
#pragma unroll 2
  for (int kb=0; kb<8; kb++){
    int cur = kb & 1;
    if (kb < 7) stage(cur^1, kb+1);
    compute(cur, 0);
    compute(cur, 1);
    __syncthreads();
  }

  float zacc = zaccA + zaccB;
  zacc += __shfl_xor(zacc, 32);

  size_t pb = ((size_t)((ksp*8+b)*8+h))*256;
#pragma unroll
  for (int dt=0;dt<2;dt++)
#pragma unroll
    for (int r=0;r<16;r++){
      int trow = 32*w + ((r&3) + 8*(r>>2) + 4*hl);
      part[(pb + trow)*64 + dt*32 + lq] = ctx[dt][r];
    }
  if (l < 32) zpart[pb + 32*w + l] = zacc;
}

// ---------------------------------------------------------------- K4a: merge 8 k-split partials -> ctx bf16
__global__ __launch_bounds__(256) void lt_mergepart(const float* __restrict__ part,
                                                    const float* __restrict__ zpart,
                                                    unsigned short* __restrict__ ctxbf){
  __shared__ float zl[64];
  int bid = blockIdx.x; int tid = threadIdx.x;
  int b = bid >> 5, h = (bid>>2)&7, tq = bid & 3;
  int tloc = tid >> 2, dq = tid & 3;
  int t = tq*64 + tloc;

  if (tid < 64){
    float z = 0.0f;
#pragma unroll
    for (int kse=0;kse<8;kse++)
      z += zpart[((size_t)((kse*8+b)*8+h))*256 + tq*64 + tid];
    zl[tid] = z;
  }
  __syncthreads();

  f32x4 s0 = zero4(), s1 = zero4(), s2 = zero4(), s3 = zero4();
#pragma unroll
  for (int kse=0;kse<8;kse++){
    const float* p = part + (((size_t)((kse*8+b)*8+h))*256 + t)*64 + dq*16;
    s0 += *(const f32x4*)(p);
    s1 += *(const f32x4*)(p+4);
    s2 += *(const f32x4*)(p+8);
    s3 += *(const f32x4*)(p+12);
  }
  float rz = 1.0f / zl[tloc];
  s0 *= rz; s1 *= rz; s2 *= rz; s3 *= rz;
  uint4v o0, o1;
  o0.x = cvt_pk_bf16(s0.x, s0.y); o0.y = cvt_pk_bf16(s0.z, s0.w);
  o0.z = cvt_pk_bf16(s1.x, s1.y); o0.w = cvt_pk_bf16(s1.z, s1.w);
  o1.x = cvt_pk_bf16(s2.x, s2.y); o1.y = cvt_pk_bf16(s2.z, s2.w);
  o1.z = cvt_pk_bf16(s3.x, s3.y); o1.w = cvt_pk_bf16(s3.z, s3.w);
  unsigned short* dst = ctxbf + (size_t)(b*256 + t)*512 + h*64 + dq*16;
  *(uint4v*)(dst)     = o0;
  *(uint4v*)(dst + 8) = o1;
}

// ---------------------------------------------------------------- K4b: out-proj GEMM (64 blocks) -> ybf
__global__ __launch_bounds__(512, 4) void lt_gemm_out(const unsigned short* __restrict__ ctxbf,
                                                      const unsigned short* __restrict__ woutbf,
                                                      unsigned short* __restrict__ ybf){
  __shared__ char smem[65536];
  int bid = blockIdx.x;
  int m0 = bid >> 2, n0 = bid & 3;
  int tid = threadIdx.x; int l = tid & 63; int w = tid >> 6;
  int wm = w >> 2, wn = w & 3;
  int l15 = l & 15, l4 = l >> 4;

  f32x4 acc[4][2];
  gemm128_body(ctxbf + (size_t)m0*128*512, woutbf + (size_t)n0*128*512, smem, tid, acc);

  int fl = wn*32 + l15;
  unsigned short* LK = (unsigned short*)smem;
#pragma unroll
  for (int mi=0;mi<4;mi++)
#pragma unroll
    for (int ni=0;ni<2;ni++)
#pragma unroll
      for (int r=0;r<4;r++){
        int row = wm*64 + mi*16 + l4*4 + r;
        int f = fl + ni*16;
        LK[row*136 + f] = bf16_1(acc[mi][ni][r]);
      }
  __syncthreads();
  size_t gbase = (size_t)m0*128*512 + n0*128;
#pragma unroll
  for (int it=0; it<4; it++){
    int ci = it*512 + tid; int row = ci>>4, c = ci&15;
    uint4v d = *(const uint4v*)(LK + row*136 + c*8);
    *(uint4v*)(ybf + gbase + (size_t)row*512 + c*8) = d;
  }
}

// ---------------------------------------------------------------- K4c: residual + bias + LayerNorm
__global__ __launch_bounds__(512) void lt_ln(const unsigned short* __restrict__ ybf,
                                             const float* __restrict__ qtok,
                                             const float* __restrict__ bout,
                                             const float* __restrict__ gamma,
                                             const float* __restrict__ beta,
                                             float* __restrict__ out){
  int tid = threadIdx.x; int l = tid & 63; int w = tid >> 6;
  int t = blockIdx.x*8 + w;
  int tok = t & 255;
  int c0 = l*8;

  short8 yb = *(const short8*)(ybf + (size_t)t*512 + c0);
  f32x4 q0 = *(const f32x4*)(qtok + (size_t)tok*512 + c0);
  f32x4 q1 = *(const f32x4*)(qtok + (size_t)tok*512 + c0 + 4);
  f32x4 b0 = *(const f32x4*)(bout + c0);
  f32x4 b1 = *(const f32x4*)(bout + c0 + 4);

  float y[8];
#pragma unroll
  for (int j=0;j<8;j++) y[j] = bf2f((unsigned short)yb[j]);
  y[0]+=q0.x+b0.x; y[1]+=q0.y+b0.y; y[2]+=q0.z+b0.z; y[3]+=q0.w+b0.w;
  y[4]+=q1.x+b1.x; y[5]+=q1.y+b1.y; y[6]+=q1.z+b1.z; y[7]+=q1.w+b1.w;

  float s1 = 0.0f, s2 = 0.0f;
#pragma unroll
  for (int j=0;j<8;j++){ s1 += y[j]; s2 += y[j]*y[j]; }
#pragma unroll
  for (int off=1; off<64; off<<=1){ s1 += __shfl_xor(s1, off); s2 += __shfl_xor(s2, off); }
  float mu = s1 * (1.0f/512.0f);
  float var = s2 * (1.0f/512.0f) - mu*mu;
  float rs = rsqrtf(var + 1e-5f);

  f32x4 g0 = *(const f32x4*)(gamma + c0);
  f32x4 g1 = *(const f32x4*)(gamma + c0 + 4);
  f32x4 e0 = *(const f32x4*)(beta + c0);
  f32x4 e1 = *(const f32x4*)(beta + c0 + 4);
  f32x4 o0, o1;
  o0.x = (y[0]-mu)*rs*g0.x + e0.x; o0.y = (y[1]-mu)*rs*g0.y + e0.y;
  o0.z = (y[2]-mu)*rs*g0.z + e0.z; o0.w = (y[3]-mu)*rs*g0.w + e0.w;
  o1.x = (y[4]-mu)*rs*g1.x + e1.x; o1.y = (y[5]-mu)*rs*g1.y + e1.y;
  o1.z = (y[6]-mu)*rs*g1.z + e1.z; o1.w = (y[7]-mu)*rs*g1.w + e1.w;
  *(f32x4*)(out + (size_t)t*512 + c0)     = o0;
  *(f32x4*)(out + (size_t)t*512 + c0 + 4) = o1;
}

// ----------------------------------------------------------------
extern "C" void kernel_launch(void* const* d_in, const int* in_sizes, int n_in,
                              void* d_out, int out_size, void* d_ws, size_t ws_size,
                              hipStream_t stream){
  (void)in_sizes; (void)n_in; (void)out_size; (void)ws_size;
  const float* x     = (const float*)d_in[0];
  const float* qtok  = (const float*)d_in[1];
  const float* inW   = (const float*)d_in[2];
  const float* inB   = (const float*)d_in[3];
  const float* outW  = (const float*)d_in[4];
  const float* outB  = (const float*)d_in[5];
  const float* gamma = (const float*)d_in[6];
  const float* beta  = (const float*)d_in[7];

  char* ws = (char*)d_ws;
  unsigned short* kbuf   = (unsigned short*)(ws);                 // 64 MB (head-major K)
  unsigned short* wqbf   = (unsigned short*)(ws);                 // 512KB alias kbuf (dead before gemm_kv)
  unsigned short* qtbf   = (unsigned short*)(ws + 524288);        // 256KB alias kbuf
  unsigned short* vtbuf  = (unsigned short*)(ws + 67108864);      // 64 MB
  unsigned short* qbuf   = (unsigned short*)(ws + 134217728);     // 256 KB
  unsigned short* wkvbf  = (unsigned short*)(ws + 134479872);     // 1 MB
  unsigned short* xbf    = (unsigned short*)(ws + 135528448);     // 64 MB (dead after gemm_kv)
  float*          partp  = (float*)(ws + 135528448);              // 32 MB (alias xbf)
  float*          zpart  = (float*)(ws + 169082880);              // 512 KB
  unsigned short* ctxbf  = (unsigned short*)(ws + 169607168);     // 2 MB
  unsigned short* ybf    = (unsigned short*)(ws + 171704320);     // 2 MB
  unsigned short* woutbf = (unsigned short*)(ws + 173801472);     // 512 KB (written after gemm_kv)

  lt_conv     <<<dim3(16384), dim3(256), 0, stream>>>(x, xbf);
  lt_conv     <<<dim3(128),   dim3(256), 0, stream>>>(inW, wqbf);
  lt_conv     <<<dim3(256),   dim3(256), 0, stream>>>(inW + 262144, wkvbf);
  lt_conv     <<<dim3(64),    dim3(256), 0, stream>>>(qtok, qtbf);
  lt_gemm_q   <<<dim3(8),     dim3(512), 0, stream>>>(qtbf, wqbf, inB, qbuf);
  lt_gemm_kv  <<<dim3(4096),  dim3(256), 0, stream>>>(xbf, wkvbf, inB, kbuf, vtbuf);
  lt_conv     <<<dim3(128),   dim3(256), 0, stream>>>(outW, woutbf);
  lt_attn     <<<dim3(512),   dim3(512), 0, stream>>>(kbuf, vtbuf, qbuf, partp, zpart);
  lt_mergepart<<<dim3(256),   dim3(256), 0, stream>>>(partp, zpart, ctxbf);
  lt_gemm_out <<<dim3(64),    dim3(512), 0, stream>>>(ctxbf, woutbf, ybf);
  lt_ln       <<<dim3(256),   dim3(512), 0, stream>>>(ybf, qtok, outB, gamma, beta, (float*)d_out);
}

// Round 13
// 206.107 us; speedup vs baseline: 1.0139x; 1.0139x over previous
//
#include <hip/hip_runtime.h>
#include <hip/hip_bf16.h>

typedef __attribute__((ext_vector_type(8)))  short        short8;
typedef __attribute__((ext_vector_type(4)))  float        f32x4;
typedef __attribute__((ext_vector_type(16))) float        f32x16;
typedef __attribute__((ext_vector_type(4)))  unsigned int uint4v;
typedef __attribute__((ext_vector_type(2)))  unsigned int uint2v;

#define MFMA16x16(a,b,c) __builtin_amdgcn_mfma_f32_16x16x32_bf16((a),(b),(c),0,0,0)
#define MFMA32x32(a,b,c) __builtin_amdgcn_mfma_f32_32x32x16_bf16((a),(b),(c),0,0,0)

__device__ __forceinline__ unsigned cvt_pk_bf16(float lo, float hi){
  unsigned r;
  asm("v_cvt_pk_bf16_f32 %0, %1, %2" : "=v"(r) : "v"(lo), "v"(hi));
  return r;
}
__device__ __forceinline__ unsigned short bf16_1(float v){
  return (unsigned short)(cvt_pk_bf16(v, v) & 0xffffu);
}
__device__ __forceinline__ float bf2f(unsigned short u){
  union { unsigned u; float f; } cv; cv.u = ((unsigned)u) << 16; return cv.f;
}
__device__ __forceinline__ void gll16(const void* src, void* dst){
  __builtin_amdgcn_global_load_lds((const __attribute__((address_space(1))) unsigned int*)src,
                                   (__attribute__((address_space(3))) unsigned int*)dst, 16, 0, 0);
}
__device__ __forceinline__ f32x16 zero16(){ f32x16 v; 
#pragma unroll
  for (int i=0;i<16;i++) v[i]=0.0f; return v; }
__device__ __forceinline__ f32x4 zero4(){ f32x4 v;
#pragma unroll
  for (int i=0;i<4;i++) v[i]=0.0f; return v; }

// 2^x for tiny |x|: 3 FMAs, no guard sequence.
__device__ __forceinline__ float exp2_tiny(float x){
  const float C1 = 0.6931471805599453f;
  const float C2 = 0.2402265069591007f;
  const float C3 = 0.0555041086648216f;
  return fmaf(x, fmaf(x, fmaf(x, C3, C2), C1), 1.0f);
}

// pi: self-inverse bit swap of bits 2 and 3
__device__ __forceinline__ int kperm(int i){
  return (i & ~12) | ((i & 4) << 1) | ((i & 8) >> 1);
}

// ---------------------------------------------------------------- generic fp32 -> bf16 (grid*256*8 elems)
__global__ void lt_conv(const float* __restrict__ src, unsigned short* __restrict__ dst){
  size_t i = ((size_t)blockIdx.x * 256 + threadIdx.x) * 8;
  f32x4 a = *(const f32x4*)(src + i);
  f32x4 b = *(const f32x4*)(src + i + 4);
  uint4v o;
  o.x = cvt_pk_bf16(a.x, a.y); o.y = cvt_pk_bf16(a.z, a.w);
  o.z = cvt_pk_bf16(b.x, b.y); o.w = cvt_pk_bf16(b.z, b.w);
  *(uint4v*)(dst + i) = o;
}

// ---------------------------------------------------------------- shared 128x128 MFMA GEMM body (BK=64, 8 waves)
__device__ __forceinline__ void gemm128_body(const unsigned short* __restrict__ atile,
                                             const unsigned short* __restrict__ btile,
                                             char* smem, int tid, f32x4 acc[4][2]){
  unsigned short* A0 = (unsigned short*)smem;            // [2][128][64]
  unsigned short* B0 = (unsigned short*)(smem + 32768);
  int l = tid & 63; int w = tid >> 6;
  int wm = w >> 2, wn = w & 3;
  int l15 = l & 15, l4 = l >> 4;

#pragma unroll
  for (int mi=0;mi<4;mi++)
#pragma unroll
    for (int ni=0;ni<2;ni++) acc[mi][ni] = zero4();

  int srow = (w*2)*8 + (l>>3);
  int gcp0 = (l&7) ^ (srow & 7);
  int srow1 = srow + 8;
  int gcp1 = (l&7) ^ (srow1 & 7);
  const unsigned short* asrc0 = atile + (size_t)srow *512 + gcp0*8;
  const unsigned short* asrc1 = atile + (size_t)srow1*512 + gcp1*8;
  const unsigned short* bsrc0 = btile + (size_t)srow *512 + gcp0*8;
  const unsigned short* bsrc1 = btile + (size_t)srow1*512 + gcp1*8;
  int ldsL = (w*2)*512;

  auto stage = [&](int buf, int k0){
    unsigned short* A = A0 + buf*8192;
    unsigned short* B = B0 + buf*8192;
    gll16(asrc0 + k0, A + ldsL);
    gll16(asrc1 + k0, A + ldsL + 512);
    gll16(bsrc0 + k0, B + ldsL);
    gll16(bsrc1 + k0, B + ldsL + 512);
  };

  stage(0, 0);
  __syncthreads();

#pragma unroll 2
  for (int t=0; t<8; t++){
    int cur = t & 1;
    if (t < 7) stage(cur^1, (t+1)*64);
    const unsigned short* A = A0 + cur*8192;
    const unsigned short* B = B0 + cur*8192;
#pragma unroll
    for (int ks=0; ks<2; ks++){
      short8 af[4], bfq[2];
#pragma unroll
      for (int mi=0;mi<4;mi++){
        int row = wm*64 + mi*16 + l15;
        int gc = ks*4 + l4;
        af[mi] = *(const short8*)(A + row*64 + ((gc ^ (row&7))<<3));
      }
#pragma unroll
      for (int ni=0;ni<2;ni++){
        int row = wn*32 + ni*16 + l15;
        int gc = ks*4 + l4;
        bfq[ni] = *(const short8*)(B + row*64 + ((gc ^ (row&7))<<3));
      }
#pragma unroll
      for (int mi=0;mi<4;mi++)
#pragma unroll
        for (int ni=0;ni<2;ni++)
          acc[mi][ni] = MFMA16x16(af[mi], bfq[ni], acc[mi][ni]);
    }
    __syncthreads();
  }
}

// ---------------------------------------------------------------- K2: KV projection GEMM (R10 form)
__global__ __launch_bounds__(512, 4) void lt_gemm_kv(const unsigned short* __restrict__ xbf,
                                                     const unsigned short* __restrict__ wkv,
                                                     const float* __restrict__ bias,
                                                     unsigned short* __restrict__ kbuf,
                                                     unsigned short* __restrict__ vtbuf){
  __shared__ char smem[65536];
  int bid = blockIdx.x;
  int xcd = bid & 7; int ii = bid >> 3;
  int m0 = xcd*64 + (ii>>3); int n0 = ii & 7;
  int tid = threadIdx.x; int l = tid & 63; int w = tid >> 6;
  int wm = w >> 2, wn = w & 3;
  int l15 = l & 15, l4 = l >> 4;

  f32x4 acc[4][2];
  gemm128_body(xbf + (size_t)m0*128*512, wkv + (size_t)n0*128*512, smem, tid, acc);

  int fl = wn*32 + l15;
  float biasr[2];
#pragma unroll
  for (int ni=0;ni<2;ni++) biasr[ni] = bias[512 + n0*128 + fl + ni*16];

  if (n0 < 4){
    unsigned short* LK = (unsigned short*)smem;   // [128][136]
#pragma unroll
    for (int mi=0;mi<4;mi++)
#pragma unroll
      for (int ni=0;ni<2;ni++)
#pragma unroll
        for (int r=0;r<4;r++){
          int row = wm*64 + mi*16 + l4*4 + r;
          int f = fl + ni*16;
          LK[row*136 + f] = bf16_1(acc[mi][ni][r] + biasr[ni]);
        }
    __syncthreads();
    int gk0 = m0*128;
#pragma unroll
    for (int it=0; it<4; it++){
      int ci = it*512 + tid; int row = ci>>4, c = ci&15;
      uint4v d = *(const uint4v*)(LK + row*136 + c*8);
      int gk = gk0 + row; int b = gk>>13; int key = gk & 8191;
      int h = 2*n0 + (c>>3); int dh = (c&7)*8;
      *(uint4v*)(kbuf + ((size_t)(b*8+h)*8192 + key)*64 + dh) = d;
    }
  } else {
    unsigned short* LT = (unsigned short*)smem;   // [128 f][128 key], swizzled
#pragma unroll
    for (int mi=0;mi<4;mi++)
#pragma unroll
      for (int ni=0;ni<2;ni++)
#pragma unroll
        for (int r=0;r<4;r++){
          int key = wm*64 + mi*16 + l4*4 + r;
          int f = fl + ni*16;
          LT[f*128 + (key ^ ((f&7)<<2))] = bf16_1(acc[mi][ni][r] + biasr[ni]);
        }
    __syncthreads();
    int bb = m0 >> 6; int key0 = (m0 & 63)*128;
#pragma unroll
    for (int it=0; it<4; it++){
      int ci = it*512 + tid; int f = ci>>4, kb = ci&15;
      int sw = (f&7)<<2;
      uint2v lo = *(const uint2v*)(LT + f*128 + ((kb*8)   ^ sw));
      uint2v hi = *(const uint2v*)(LT + f*128 + ((kb*8+4) ^ sw));
      int vf = (n0-4)*128 + f; int hv = vf>>6, dh = vf&63;
      uint4v d; d.x = lo.x; d.y = lo.y; d.z = hi.x; d.w = hi.y;
      *(uint4v*)(vtbuf + ((size_t)((bb*8+hv)*64+dh))*8192 + key0 + kb*8) = d;
    }
  }
}

// ---------------------------------------------------------------- K1: q projection GEMM (8 blocks)
__global__ __launch_bounds__(512, 4) void lt_gemm_q(const unsigned short* __restrict__ qtbf,
                                                    const unsigned short* __restrict__ wqbf,
                                                    const float* __restrict__ bias,
                                                    unsigned short* __restrict__ qbuf){
  __shared__ char smem[65536];
  int bid = blockIdx.x;
  int m0 = bid >> 2, n0 = bid & 3;
  int tid = threadIdx.x; int l = tid & 63; int w = tid >> 6;
  int wm = w >> 2, wn = w & 3;
  int l15 = l & 15, l4 = l >> 4;

  f32x4 acc[4][2];
  gemm128_body(qtbf + (size_t)m0*128*512, wqbf + (size_t)n0*128*512, smem, tid, acc);

  const float SC = 0.18033688011112042f;   // log2(e)/sqrt(64)
  int fl = wn*32 + l15;
  float biasr[2];
#pragma unroll
  for (int ni=0;ni<2;ni++) biasr[ni] = bias[n0*128 + fl + ni*16];

  unsigned short* LK = (unsigned short*)smem;
#pragma unroll
  for (int mi=0;mi<4;mi++)
#pragma unroll
    for (int ni=0;ni<2;ni++)
#pragma unroll
      for (int r=0;r<4;r++){
        int row = wm*64 + mi*16 + l4*4 + r;
        int f = fl + ni*16;
        LK[row*136 + f] = bf16_1((acc[mi][ni][r] + biasr[ni]) * SC);
      }
  __syncthreads();
  size_t gbase = (size_t)m0*128*512 + n0*128;
#pragma unroll
  for (int it=0; it<4; it++){
    int ci = it*512 + tid; int row = ci>>4, c = ci&15;
    uint4v d = *(const uint4v*)(LK + row*136 + c*8);
    *(uint4v*)(qbuf + gbase + (size_t)row*512 + c*8) = d;
  }
}

// ---------------------------------------------------------------- K3: flash attention (bf16 partials)
__global__ __launch_bounds__(512, 4) void lt_attn(const unsigned short* __restrict__ kbuf,
                                                  const unsigned short* __restrict__ vtbuf,
                                                  const unsigned short* __restrict__ qbuf,
                                                  unsigned short* __restrict__ partb,
                                                  float* __restrict__ zpart){
  __shared__ unsigned short lds[32768];
  int bid = blockIdx.x;
  int ksp = bid & 7, h = (bid>>3)&7, b = bid>>6;
  int tid = threadIdx.x; int l = tid & 63; int w = tid >> 6;
  int lq = l & 31, hl = l >> 5;
  int key_base = ksp*1024;

  short8 qf[4];
#pragma unroll
  for (int ks=0;ks<4;ks++){
    int t = 32*w + lq;
    qf[ks] = *(const short8*)(qbuf + (size_t)t*512 + h*64 + ks*16 + 8*hl);
  }

  f32x16 ctx[2]; ctx[0] = zero16(); ctx[1] = zero16();
  float zaccA = 0.0f, zaccB = 0.0f;

  int krow  = w*16 + (l>>3);
  int kgcp0 = (l&7) ^ (krow & 7);
  int krow1 = krow + 8;
  int kgcp1 = (l&7) ^ (krow1 & 7);
  const unsigned short* khead = kbuf + ((size_t)(b*8+h)*8192 + key_base)*64;
  const unsigned short* ksrc0 = khead + (size_t)kperm(krow )*64 + kgcp0*8;
  const unsigned short* ksrc1 = khead + (size_t)kperm(krow1)*64 + kgcp1*8;
  int vrow = w*8 + (l>>3);
  int vgcp = (l&7) ^ (vrow & 7);
  const unsigned short* vsrc = vtbuf + (size_t)((b*8+h)*64 + vrow)*8192 + key_base + vgcp*8;

  auto stage = [&](int buf, int kb){
    unsigned short* base = lds + buf*16384;
    size_t koff = (size_t)kb*128*64;
    gll16(ksrc0 + koff, base + (w*2  )*512);
    gll16(ksrc1 + koff, base + (w*2+1)*512);
    gll16(vsrc + kb*128,      base + 8192  + w*512);
    gll16(vsrc + kb*128 + 64, base + 12288 + w*512);
  };

  auto compute = [&](int buf, int sub){
    const unsigned short* baseK = lds + buf*16384 + sub*4096;
    const unsigned short* baseV = lds + buf*16384 + 8192 + sub*4096;
    f32x16 st[2];
    short8 kfk[4];
    __builtin_amdgcn_s_setprio(1);
#pragma unroll
    for (int kt=0;kt<2;kt++){
#pragma unroll
      for (int ks=0;ks<4;ks++){
        int row = kt*32 + lq;
        int gc = 2*ks + hl;
        kfk[ks] = *(const short8*)(baseK + row*64 + ((gc ^ (row&7))<<3));
      }
      st[kt] = zero16();
#pragma unroll
      for (int ks=0;ks<4;ks++)
        st[kt] = MFMA32x32(kfk[ks], qf[ks], st[kt]);
    }
    __builtin_amdgcn_s_setprio(0);
#pragma unroll
    for (int r=0;r<16;r++){
      float e0 = exp2_tiny(st[0][r]);
      float e1 = exp2_tiny(st[1][r]);
      st[0][r] = e0; zaccA += e0;
      st[1][r] = e1; zaccB += e1;
    }
    __builtin_amdgcn_s_setprio(1);
#pragma unroll
    for (int ks=0;ks<4;ks++){
      int kt = ks>>1, o = (ks&1)*8;
      int gc = 2*ks + hl;
      int row0 = lq, row1 = 32 + lq;
      short8 v0 = *(const short8*)(baseV + row0*64 + ((gc ^ (row0&7))<<3));
      short8 v1 = *(const short8*)(baseV + row1*64 + ((gc ^ (row1&7))<<3));
      uint4v pw;
      pw.x = cvt_pk_bf16(st[kt][o+0], st[kt][o+1]);
      pw.y = cvt_pk_bf16(st[kt][o+2], st[kt][o+3]);
      pw.z = cvt_pk_bf16(st[kt][o+4], st[kt][o+5]);
      pw.w = cvt_pk_bf16(st[kt][o+6], st[kt][o+7]);
      union { uint4v u; short8 s; } pc; pc.u = pw;
      ctx[0] = MFMA32x32(pc.s, v0, ctx[0]);
      ctx[1] = MFMA32x32(pc.s, v1, ctx[1]);
    }
    __builtin_amdgcn_s_setprio(0);
  };

  stage(0, 0);
  __syncthreads();
#pragma unroll 2
  for (int kb=0; kb<8; kb++){
    int cur = kb & 1;
    if (kb < 7) stage(cur^1, kb+1);
    compute(cur, 0);
    compute(cur, 1);
    __syncthreads();
  }

  float zacc = zaccA + zaccB;
  zacc += __shfl_xor(zacc, 32);

  size_t pb = ((size_t)((ksp*8+b)*8+h))*256;
#pragma unroll
  for (int dt=0;dt<2;dt++)
#pragma unroll
    for (int r=0;r<16;r++){
      int trow = 32*w + ((r&3) + 8*(r>>2) + 4*hl);
      partb[(pb + trow)*64 + dt*32 + lq] = bf16_1(ctx[dt][r]);
    }
  if (l < 32) zpart[pb + 32*w + l] = zacc;
}

// ---------------------------------------------------------------- K4a: merge 8 k-split bf16 partials -> ctx bf16
__global__ __launch_bounds__(256) void lt_mergepart(const unsigned short* __restrict__ partb,
                                                    const float* __restrict__ zpart,
                                                    unsigned short* __restrict__ ctxbf){
  __shared__ float zl[64];
  int bid = blockIdx.x; int tid = threadIdx.x;
  int b = bid >> 5, h = (bid>>2)&7, tq = bid & 3;
  int tloc = tid >> 2, dq = tid & 3;
  int t = tq*64 + tloc;

  if (tid < 64){
    float z = 0.0f;
#pragma unroll
    for (int kse=0;kse<8;kse++)
      z += zpart[((size_t)((kse*8+b)*8+h))*256 + tq*64 + tid];
    zl[tid] = z;
  }
  __syncthreads();

  float s[16];
#pragma unroll
  for (int j=0;j<16;j++) s[j] = 0.0f;
#pragma unroll
  for (int kse=0;kse<8;kse++){
    const unsigned short* p = partb + (((size_t)((kse*8+b)*8+h))*256 + t)*64 + dq*16;
    short8 u0 = *(const short8*)(p);
    short8 u1 = *(const short8*)(p + 8);
#pragma unroll
    for (int j=0;j<8;j++){
      s[j]   += bf2f((unsigned short)u0[j]);
      s[j+8] += bf2f((unsigned short)u1[j]);
    }
  }
  float rz = 1.0f / zl[tloc];
  uint4v o0, o1;
  o0.x = cvt_pk_bf16(s[0]*rz,  s[1]*rz);  o0.y = cvt_pk_bf16(s[2]*rz,  s[3]*rz);
  o0.z = cvt_pk_bf16(s[4]*rz,  s[5]*rz);  o0.w = cvt_pk_bf16(s[6]*rz,  s[7]*rz);
  o1.x = cvt_pk_bf16(s[8]*rz,  s[9]*rz);  o1.y = cvt_pk_bf16(s[10]*rz, s[11]*rz);
  o1.z = cvt_pk_bf16(s[12]*rz, s[13]*rz); o1.w = cvt_pk_bf16(s[14]*rz, s[15]*rz);
  unsigned short* dst = ctxbf + (size_t)(b*256 + t)*512 + h*64 + dq*16;
  *(uint4v*)(dst)     = o0;
  *(uint4v*)(dst + 8) = o1;
}

// ---------------------------------------------------------------- K4b: out-proj GEMM (64 blocks) -> ybf
__global__ __launch_bounds__(512, 4) void lt_gemm_out(const unsigned short* __restrict__ ctxbf,
                                                      const unsigned short* __restrict__ woutbf,
                                                      unsigned short* __restrict__ ybf){
  __shared__ char smem[65536];
  int bid = blockIdx.x;
  int m0 = bid >> 2, n0 = bid & 3;
  int tid = threadIdx.x; int l = tid & 63; int w = tid >> 6;
  int wm = w >> 2, wn = w & 3;
  int l15 = l & 15, l4 = l >> 4;

  f32x4 acc[4][2];
  gemm128_body(ctxbf + (size_t)m0*128*512, woutbf + (size_t)n0*128*512, smem, tid, acc);

  int fl = wn*32 + l15;
  unsigned short* LK = (unsigned short*)smem;
#pragma unroll
  for (int mi=0;mi<4;mi++)
#pragma unroll
    for (int ni=0;ni<2;ni++)
#pragma unroll
      for (int r=0;r<4;r++){
        int row = wm*64 + mi*16 + l4*4 + r;
        int f = fl + ni*16;
        LK[row*136 + f] = bf16_1(acc[mi][ni][r]);
      }
  __syncthreads();
  size_t gbase = (size_t)m0*128*512 + n0*128;
#pragma unroll
  for (int it=0; it<4; it++){
    int ci = it*512 + tid; int row = ci>>4, c = ci&15;
    uint4v d = *(const uint4v*)(LK + row*136 + c*8);
    *(uint4v*)(ybf + gbase + (size_t)row*512 + c*8) = d;
  }
}

// ---------------------------------------------------------------- K4c: residual + bias + LayerNorm
__global__ __launch_bounds__(512) void lt_ln(const unsigned short* __restrict__ ybf,
                                             const float* __restrict__ qtok,
                                             const float* __restrict__ bout,
                                             const float* __restrict__ gamma,
                                             const float* __restrict__ beta,
                                             float* __restrict__ out){
  int tid = threadIdx.x; int l = tid & 63; int w = tid >> 6;
  int t = blockIdx.x*8 + w;
  int tok = t & 255;
  int c0 = l*8;

  short8 yb = *(const short8*)(ybf + (size_t)t*512 + c0);
  f32x4 q0 = *(const f32x4*)(qtok + (size_t)tok*512 + c0);
  f32x4 q1 = *(const f32x4*)(qtok + (size_t)tok*512 + c0 + 4);
  f32x4 b0 = *(const f32x4*)(bout + c0);
  f32x4 b1 = *(const f32x4*)(bout + c0 + 4);

  float y[8];
#pragma unroll
  for (int j=0;j<8;j++) y[j] = bf2f((unsigned short)yb[j]);
  y[0]+=q0.x+b0.x; y[1]+=q0.y+b0.y; y[2]+=q0.z+b0.z; y[3]+=q0.w+b0.w;
  y[4]+=q1.x+b1.x; y[5]+=q1.y+b1.y; y[6]+=q1.z+b1.z; y[7]+=q1.w+b1.w;

  float s1 = 0.0f, s2 = 0.0f;
#pragma unroll
  for (int j=0;j<8;j++){ s1 += y[j]; s2 += y[j]*y[j]; }
#pragma unroll
  for (int off=1; off<64; off<<=1){ s1 += __shfl_xor(s1, off); s2 += __shfl_xor(s2, off); }
  float mu = s1 * (1.0f/512.0f);
  float var = s2 * (1.0f/512.0f) - mu*mu;
  float rs = rsqrtf(var + 1e-5f);

  f32x4 g0 = *(const f32x4*)(gamma + c0);
  f32x4 g1 = *(const f32x4*)(gamma + c0 + 4);
  f32x4 e0 = *(const f32x4*)(beta + c0);
  f32x4 e1 = *(const f32x4*)(beta + c0 + 4);
  f32x4 o0, o1;
  o0.x = (y[0]-mu)*rs*g0.x + e0.x; o0.y = (y[1]-mu)*rs*g0.y + e0.y;
  o0.z = (y[2]-mu)*rs*g0.z + e0.z; o0.w = (y[3]-mu)*rs*g0.w + e0.w;
  o1.x = (y[4]-mu)*rs*g1.x + e1.x; o1.y = (y[5]-mu)*rs*g1.y + e1.y;
  o1.z = (y[6]-mu)*rs*g1.z + e1.z; o1.w = (y[7]-mu)*rs*g1.w + e1.w;
  *(f32x4*)(out + (size_t)t*512 + c0)     = o0;
  *(f32x4*)(out + (size_t)t*512 + c0 + 4) = o1;
}

// ----------------------------------------------------------------
extern "C" void kernel_launch(void* const* d_in, const int* in_sizes, int n_in,
                              void* d_out, int out_size, void* d_ws, size_t ws_size,
                              hipStream_t stream){
  (void)in_sizes; (void)n_in; (void)out_size; (void)ws_size;
  const float* x     = (const float*)d_in[0];
  const float* qtok  = (const float*)d_in[1];
  const float* inW   = (const float*)d_in[2];
  const float* inB   = (const float*)d_in[3];
  const float* outW  = (const float*)d_in[4];
  const float* outB  = (const float*)d_in[5];
  const float* gamma = (const float*)d_in[6];
  const float* beta  = (const float*)d_in[7];

  char* ws = (char*)d_ws;
  // kbuf: 64MB head-major K. wq/qt alias its head but are fully consumed by
  // lt_gemm_q BEFORE lt_gemm_kv launches (cross-launch dead -> safe).
  // wkvbf must NOT alias kbuf: lt_gemm_kv reads it while writing kbuf (R12 race).
  unsigned short* kbuf   = (unsigned short*)(ws);                 // 64 MB
  unsigned short* wqbf   = (unsigned short*)(ws);                 // 512 KB alias kbuf
  unsigned short* qtbf   = (unsigned short*)(ws + 524288);        // 256 KB alias kbuf
  unsigned short* vtbuf  = (unsigned short*)(ws + 67108864);      // 64 MB
  unsigned short* qbuf   = (unsigned short*)(ws + 134217728);     // 256 KB
  unsigned short* wkvbf  = (unsigned short*)(ws + 134479872);     // 1 MB standalone
  unsigned short* xbf    = (unsigned short*)(ws + 135528448);     // 64 MB (dead after gemm_kv)
  unsigned short* partb  = (unsigned short*)(ws + 135528448);     // 16 MB (alias xbf)
  float*          zpart  = (float*)(ws + 169082880);              // 512 KB (inside dead xbf)
  unsigned short* ctxbf  = (unsigned short*)(ws + 169607168);     // 2 MB (inside dead xbf)
  unsigned short* ybf    = (unsigned short*)(ws + 171704320);     // 2 MB (inside dead xbf)
  unsigned short* woutbf = (unsigned short*)(ws + 173801472);     // 512 KB (inside dead xbf; written after gemm_kv)

  lt_conv     <<<dim3(16384), dim3(256), 0, stream>>>(x, xbf);
  lt_conv     <<<dim3(128),   dim3(256), 0, stream>>>(inW, wqbf);
  lt_conv     <<<dim3(256),   dim3(256), 0, stream>>>(inW + 262144, wkvbf);
  lt_conv     <<<dim3(64),    dim3(256), 0, stream>>>(qtok, qtbf);
  lt_gemm_q   <<<dim3(8),     dim3(512), 0, stream>>>(qtbf, wqbf, inB, qbuf);
  lt_gemm_kv  <<<dim3(4096),  dim3(512), 0, stream>>>(xbf, wkvbf, inB, kbuf, vtbuf);
  lt_conv     <<<dim3(128),   dim3(256), 0, stream>>>(outW, woutbf);
  lt_attn     <<<dim3(512),   dim3(512), 0, stream>>>(kbuf, vtbuf, qbuf, partb, zpart);
  lt_mergepart<<<dim3(256),   dim3(256), 0, stream>>>(partb, zpart, ctxbf);
  lt_gemm_out <<<dim3(64),    dim3(512), 0, stream>>>(ctxbf, woutbf, ybf);
  lt_ln       <<<dim3(256),   dim3(512), 0, stream>>>(ybf, qtok, outB, gamma, beta, (float*)d_out);
}

// Round 14
// 202.114 us; speedup vs baseline: 1.0339x; 1.0198x over previous
//
#include <hip/hip_runtime.h>
#include <hip/hip_bf16.h>

typedef __attribute__((ext_vector_type(8)))  short        short8;
typedef __attribute__((ext_vector_type(4)))  float        f32x4;
typedef __attribute__((ext_vector_type(16))) float        f32x16;
typedef __attribute__((ext_vector_type(4)))  unsigned int uint4v;
typedef __attribute__((ext_vector_type(2)))  unsigned int uint2v;

#define MFMA16x16(a,b,c) __builtin_amdgcn_mfma_f32_16x16x32_bf16((a),(b),(c),0,0,0)
#define MFMA32x32(a,b,c) __builtin_amdgcn_mfma_f32_32x32x16_bf16((a),(b),(c),0,0,0)

__device__ __forceinline__ unsigned cvt_pk_bf16(float lo, float hi){
  unsigned r;
  asm("v_cvt_pk_bf16_f32 %0, %1, %2" : "=v"(r) : "v"(lo), "v"(hi));
  return r;
}
__device__ __forceinline__ unsigned short bf16_1(float v){
  return (unsigned short)(cvt_pk_bf16(v, v) & 0xffffu);
}
__device__ __forceinline__ float bf2f(unsigned short u){
  union { unsigned u; float f; } cv; cv.u = ((unsigned)u) << 16; return cv.f;
}
__device__ __forceinline__ void gll16(const void* src, void* dst){
  __builtin_amdgcn_global_load_lds((const __attribute__((address_space(1))) unsigned int*)src,
                                   (__attribute__((address_space(3))) unsigned int*)dst, 16, 0, 0);
}
__device__ __forceinline__ f32x16 zero16(){ f32x16 v; 
#pragma unroll
  for (int i=0;i<16;i++) v[i]=0.0f; return v; }
__device__ __forceinline__ f32x4 zero4(){ f32x4 v;
#pragma unroll
  for (int i=0;i<4;i++) v[i]=0.0f; return v; }

// 2^x for tiny |x|: 3 FMAs, no guard sequence.
__device__ __forceinline__ float exp2_tiny(float x){
  const float C1 = 0.6931471805599453f;
  const float C2 = 0.2402265069591007f;
  const float C3 = 0.0555041086648216f;
  return fmaf(x, fmaf(x, fmaf(x, C3, C2), C1), 1.0f);
}

// pi: self-inverse bit swap of bits 2 and 3
__device__ __forceinline__ int kperm(int i){
  return (i & ~12) | ((i & 4) << 1) | ((i & 8) >> 1);
}

// ---------------------------------------------------------------- generic fp32 -> bf16 (grid*256*8 elems)
__global__ void lt_conv(const float* __restrict__ src, unsigned short* __restrict__ dst){
  size_t i = ((size_t)blockIdx.x * 256 + threadIdx.x) * 8;
  f32x4 a = *(const f32x4*)(src + i);
  f32x4 b = *(const f32x4*)(src + i + 4);
  uint4v o;
  o.x = cvt_pk_bf16(a.x, a.y); o.y = cvt_pk_bf16(a.z, a.w);
  o.z = cvt_pk_bf16(b.x, b.y); o.w = cvt_pk_bf16(b.z, b.w);
  *(uint4v*)(dst + i) = o;
}

// ---------------------------------------------------------------- shared 128x128 MFMA GEMM body (BK=64, 8 waves)
// 2-phase form, used by the small GEMMs (qproj, out-proj).
__device__ __forceinline__ void gemm128_body(const unsigned short* __restrict__ atile,
                                             const unsigned short* __restrict__ btile,
                                             char* smem, int tid, f32x4 acc[4][2]){
  unsigned short* A0 = (unsigned short*)smem;            // [2][128][64]
  unsigned short* B0 = (unsigned short*)(smem + 32768);
  int l = tid & 63; int w = tid >> 6;
  int wm = w >> 2, wn = w & 3;
  int l15 = l & 15, l4 = l >> 4;

#pragma unroll
  for (int mi=0;mi<4;mi++)
#pragma unroll
    for (int ni=0;ni<2;ni++) acc[mi][ni] = zero4();

  int srow = (w*2)*8 + (l>>3);
  int gcp0 = (l&7) ^ (srow & 7);
  int srow1 = srow + 8;
  int gcp1 = (l&7) ^ (srow1 & 7);
  const unsigned short* asrc0 = atile + (size_t)srow *512 + gcp0*8;
  const unsigned short* asrc1 = atile + (size_t)srow1*512 + gcp1*8;
  const unsigned short* bsrc0 = btile + (size_t)srow *512 + gcp0*8;
  const unsigned short* bsrc1 = btile + (size_t)srow1*512 + gcp1*8;
  int ldsL = (w*2)*512;

  auto stage = [&](int buf, int k0){
    unsigned short* A = A0 + buf*8192;
    unsigned short* B = B0 + buf*8192;
    gll16(asrc0 + k0, A + ldsL);
    gll16(asrc1 + k0, A + ldsL + 512);
    gll16(bsrc0 + k0, B + ldsL);
    gll16(bsrc1 + k0, B + ldsL + 512);
  };

  stage(0, 0);
  __syncthreads();

#pragma unroll 2
  for (int t=0; t<8; t++){
    int cur = t & 1;
    if (t < 7) stage(cur^1, (t+1)*64);
    const unsigned short* A = A0 + cur*8192;
    const unsigned short* B = B0 + cur*8192;
#pragma unroll
    for (int ks=0; ks<2; ks++){
      short8 af[4], bfq[2];
#pragma unroll
      for (int mi=0;mi<4;mi++){
        int row = wm*64 + mi*16 + l15;
        int gc = ks*4 + l4;
        af[mi] = *(const short8*)(A + row*64 + ((gc ^ (row&7))<<3));
      }
#pragma unroll
      for (int ni=0;ni<2;ni++){
        int row = wn*32 + ni*16 + l15;
        int gc = ks*4 + l4;
        bfq[ni] = *(const short8*)(B + row*64 + ((gc ^ (row&7))<<3));
      }
#pragma unroll
      for (int mi=0;mi<4;mi++)
#pragma unroll
        for (int ni=0;ni<2;ni++)
          acc[mi][ni] = MFMA16x16(af[mi], bfq[ni], acc[mi][ni]);
    }
    __syncthreads();
  }
}

// ---------------------------------------------------------------- K2: KV projection GEMM
// Depth-2 counted-vmcnt pipeline (T3/T4 minimum form): two K-tiles in flight,
// vmcnt(4) waits only the OLDEST tile's loads; loads get a full iteration to land.
__global__ __launch_bounds__(512, 4) void lt_gemm_kv(const unsigned short* __restrict__ xbf,
                                                     const unsigned short* __restrict__ wkv,
                                                     const float* __restrict__ bias,
                                                     unsigned short* __restrict__ kbuf,
                                                     unsigned short* __restrict__ vtbuf){
  __shared__ char smem[65536];
  unsigned short* A0 = (unsigned short*)smem;            // [2][128][64]
  unsigned short* B0 = (unsigned short*)(smem + 32768);

  int bid = blockIdx.x;
  int xcd = bid & 7; int ii = bid >> 3;
  int m0 = xcd*64 + (ii>>3); int n0 = ii & 7;
  int tid = threadIdx.x; int l = tid & 63; int w = tid >> 6;
  int wm = w >> 2, wn = w & 3;
  int l15 = l & 15, l4 = l >> 4;

  f32x4 acc[4][2];
#pragma unroll
  for (int mi=0;mi<4;mi++)
#pragma unroll
    for (int ni=0;ni<2;ni++) acc[mi][ni] = zero4();

  int srow = (w*2)*8 + (l>>3);
  int gcp0 = (l&7) ^ (srow & 7);
  int srow1 = srow + 8;
  int gcp1 = (l&7) ^ (srow1 & 7);
  const unsigned short* asrc0 = xbf + (size_t)(m0*128 + srow )*512 + gcp0*8;
  const unsigned short* asrc1 = xbf + (size_t)(m0*128 + srow1)*512 + gcp1*8;
  const unsigned short* bsrc0 = wkv + (size_t)(n0*128 + srow )*512 + gcp0*8;
  const unsigned short* bsrc1 = wkv + (size_t)(n0*128 + srow1)*512 + gcp1*8;
  int ldsL = (w*2)*512;

  auto stage = [&](int buf, int k0){
    unsigned short* A = A0 + buf*8192;
    unsigned short* B = B0 + buf*8192;
    gll16(asrc0 + k0, A + ldsL);
    gll16(asrc1 + k0, A + ldsL + 512);
    gll16(bsrc0 + k0, B + ldsL);
    gll16(bsrc1 + k0, B + ldsL + 512);
  };

  // prologue: two tiles in flight (8 loads/thread outstanding)
  stage(0, 0);
  stage(1, 64);

#pragma unroll
  for (int t=0; t<8; t++){
    int cur = t & 1;
    // wait only the oldest tile's loads (4); tile t+1 stays in flight across the barrier
    if (t == 7) { asm volatile("s_waitcnt vmcnt(0)" ::: "memory"); }
    else        { asm volatile("s_waitcnt vmcnt(4)" ::: "memory"); }
    __builtin_amdgcn_s_barrier();

    const unsigned short* A = A0 + cur*8192;
    const unsigned short* B = B0 + cur*8192;
    __builtin_amdgcn_s_setprio(1);
#pragma unroll
    for (int ks=0; ks<2; ks++){
      short8 af[4], bfq[2];
#pragma unroll
      for (int mi=0;mi<4;mi++){
        int row = wm*64 + mi*16 + l15;
        int gc = ks*4 + l4;
        af[mi] = *(const short8*)(A + row*64 + ((gc ^ (row&7))<<3));
      }
#pragma unroll
      for (int ni=0;ni<2;ni++){
        int row = wn*32 + ni*16 + l15;
        int gc = ks*4 + l4;
        bfq[ni] = *(const short8*)(B + row*64 + ((gc ^ (row&7))<<3));
      }
#pragma unroll
      for (int mi=0;mi<4;mi++)
#pragma unroll
        for (int ni=0;ni<2;ni++)
          acc[mi][ni] = MFMA16x16(af[mi], bfq[ni], acc[mi][ni]);
    }
    __builtin_amdgcn_s_setprio(0);

    // all my LDS reads done, then sync, then refill this buffer with tile t+2
    asm volatile("s_waitcnt lgkmcnt(0)" ::: "memory");
    __builtin_amdgcn_s_barrier();
    if (t < 6) stage(cur, (t+2)*64);
  }

  // ---- epilogue (loop exits barrier-synced; LDS reusable)
  int fl = wn*32 + l15;
  float biasr[2];
#pragma unroll
  for (int ni=0;ni<2;ni++) biasr[ni] = bias[512 + n0*128 + fl + ni*16];

  if (n0 < 4){
    unsigned short* LK = (unsigned short*)smem;   // [128][136]
#pragma unroll
    for (int mi=0;mi<4;mi++)
#pragma unroll
      for (int ni=0;ni<2;ni++)
#pragma unroll
        for (int r=0;r<4;r++){
          int row = wm*64 + mi*16 + l4*4 + r;
          int f = fl + ni*16;
          LK[row*136 + f] = bf16_1(acc[mi][ni][r] + biasr[ni]);
        }
    __syncthreads();
    int gk0 = m0*128;
#pragma unroll
    for (int it=0; it<4; it++){
      int ci = it*512 + tid; int row = ci>>4, c = ci&15;
      uint4v d = *(const uint4v*)(LK + row*136 + c*8);
      int gk = gk0 + row; int b = gk>>13; int key = gk & 8191;
      int h = 2*n0 + (c>>3); int dh = (c&7)*8;
      *(uint4v*)(kbuf + ((size_t)(b*8+h)*8192 + key)*64 + dh) = d;
    }
  } else {
    unsigned short* LT = (unsigned short*)smem;   // [128 f][128 key], swizzled
#pragma unroll
    for (int mi=0;mi<4;mi++)
#pragma unroll
      for (int ni=0;ni<2;ni++)
#pragma unroll
        for (int r=0;r<4;r++){
          int key = wm*64 + mi*16 + l4*4 + r;
          int f = fl + ni*16;
          LT[f*128 + (key ^ ((f&7)<<2))] = bf16_1(acc[mi][ni][r] + biasr[ni]);
        }
    __syncthreads();
    int bb = m0 >> 6; int key0 = (m0 & 63)*128;
#pragma unroll
    for (int it=0; it<4; it++){
      int ci = it*512 + tid; int f = ci>>4, kb = ci&15;
      int sw = (f&7)<<2;
      uint2v lo = *(const uint2v*)(LT + f*128 + ((kb*8)   ^ sw));
      uint2v hi = *(const uint2v*)(LT + f*128 + ((kb*8+4) ^ sw));
      int vf = (n0-4)*128 + f; int hv = vf>>6, dh = vf&63;
      uint4v d; d.x = lo.x; d.y = lo.y; d.z = hi.x; d.w = hi.y;
      *(uint4v*)(vtbuf + ((size_t)((bb*8+hv)*64+dh))*8192 + key0 + kb*8) = d;
    }
  }
}

// ---------------------------------------------------------------- K1: q projection GEMM (8 blocks)
__global__ __launch_bounds__(512, 4) void lt_gemm_q(const unsigned short* __restrict__ qtbf,
                                                    const unsigned short* __restrict__ wqbf,
                                                    const float* __restrict__ bias,
                                                    unsigned short* __restrict__ qbuf){
  __shared__ char smem[65536];
  int bid = blockIdx.x;
  int m0 = bid >> 2, n0 = bid & 3;
  int tid = threadIdx.x; int l = tid & 63; int w = tid >> 6;
  int wm = w >> 2, wn = w & 3;
  int l15 = l & 15, l4 = l >> 4;

  f32x4 acc[4][2];
  gemm128_body(qtbf + (size_t)m0*128*512, wqbf + (size_t)n0*128*512, smem, tid, acc);

  const float SC = 0.18033688011112042f;   // log2(e)/sqrt(64)
  int fl = wn*32 + l15;
  float biasr[2];
#pragma unroll
  for (int ni=0;ni<2;ni++) biasr[ni] = bias[n0*128 + fl + ni*16];

  unsigned short* LK = (unsigned short*)smem;
#pragma unroll
  for (int mi=0;mi<4;mi++)
#pragma unroll
    for (int ni=0;ni<2;ni++)
#pragma unroll
      for (int r=0;r<4;r++){
        int row = wm*64 + mi*16 + l4*4 + r;
        int f = fl + ni*16;
        LK[row*136 + f] = bf16_1((acc[mi][ni][r] + biasr[ni]) * SC);
      }
  __syncthreads();
  size_t gbase = (size_t)m0*128*512 + n0*128;
#pragma unroll
  for (int it=0; it<4; it++){
    int ci = it*512 + tid; int row = ci>>4, c = ci&15;
    uint4v d = *(const uint4v*)(LK + row*136 + c*8);
    *(uint4v*)(qbuf + gbase + (size_t)row*512 + c*8) = d;
  }
}

// ---------------------------------------------------------------- K3: flash attention (bf16 partials)
__global__ __launch_bounds__(512, 4) void lt_attn(const unsigned short* __restrict__ kbuf,
                                                  const unsigned short* __restrict__ vtbuf,
                                                  const unsigned short* __restrict__ qbuf,
                                                  unsigned short* __restrict__ partb,
                                                  float* __restrict__ zpart){
  __shared__ unsigned short lds[32768];
  int bid = blockIdx.x;
  int ksp = bid & 7, h = (bid>>3)&7, b = bid>>6;
  int tid = threadIdx.x; int l = tid & 63; int w = tid >> 6;
  int lq = l & 31, hl = l >> 5;
  int key_base = ksp*1024;

  short8 qf[4];
#pragma unroll
  for (int ks=0;ks<4;ks++){
    int t = 32*w + lq;
    qf[ks] = *(const short8*)(qbuf + (size_t)t*512 + h*64 + ks*16 + 8*hl);
  }

  f32x16 ctx[2]; ctx[0] = zero16(); ctx[1] = zero16();
  float zaccA = 0.0f, zaccB = 0.0f;

  int krow  = w*16 + (l>>3);
  int kgcp0 = (l&7) ^ (krow & 7);
  int krow1 = krow + 8;
  int kgcp1 = (l&7) ^ (krow1 & 7);
  const unsigned short* khead = kbuf + ((size_t)(b*8+h)*8192 + key_base)*64;
  const unsigned short* ksrc0 = khead + (size_t)kperm(krow )*64 + kgcp0*8;
  const unsigned short* ksrc1 = khead + (size_t)kperm(krow1)*64 + kgcp1*8;
  int vrow = w*8 + (l>>3);
  int vgcp = (l&7) ^ (vrow & 7);
  const unsigned short* vsrc = vtbuf + (size_t)((b*8+h)*64 + vrow)*8192 + key_base + vgcp*8;

  auto stage = [&](int buf, int kb){
    unsigned short* base = lds + buf*16384;
    size_t koff = (size_t)kb*128*64;
    gll16(ksrc0 + koff, base + (w*2  )*512);
    gll16(ksrc1 + koff, base + (w*2+1)*512);
    gll16(vsrc + kb*128,      base + 8192  + w*512);
    gll16(vsrc + kb*128 + 64, base + 12288 + w*512);
  };

  auto compute = [&](int buf, int sub){
    const unsigned short* baseK = lds + buf*16384 + sub*4096;
    const unsigned short* baseV = lds + buf*16384 + 8192 + sub*4096;
    f32x16 st[2];
    short8 kfk[4];
    __builtin_amdgcn_s_setprio(1);
#pragma unroll
    for (int kt=0;kt<2;kt++){
#pragma unroll
      for (int ks=0;ks<4;ks++){
        int row = kt*32 + lq;
        int gc = 2*ks + hl;
        kfk[ks] = *(const short8*)(baseK + row*64 + ((gc ^ (row&7))<<3));
      }
      st[kt] = zero16();
#pragma unroll
      for (int ks=0;ks<4;ks++)
        st[kt] = MFMA32x32(kfk[ks], qf[ks], st[kt]);
    }
    __builtin_amdgcn_s_setprio(0);
#pragma unroll
    for (int r=0;r<16;r++){
      float e0 = exp2_tiny(st[0][r]);
      float e1 = exp2_tiny(st[1][r]);
      st[0][r] = e0; zaccA += e0;
      st[1][r] = e1; zaccB += e1;
    }
    __builtin_amdgcn_s_setprio(1);
#pragma unroll
    for (int ks=0;ks<4;ks++){
      int kt = ks>>1, o = (ks&1)*8;
      int gc = 2*ks + hl;
      int row0 = lq, row1 = 32 + lq;
      short8 v0 = *(const short8*)(baseV + row0*64 + ((gc ^ (row0&7))<<3));
      short8 v1 = *(const short8*)(baseV + row1*64 + ((gc ^ (row1&7))<<3));
      uint4v pw;
      pw.x = cvt_pk_bf16(st[kt][o+0], st[kt][o+1]);
      pw.y = cvt_pk_bf16(st[kt][o+2], st[kt][o+3]);
      pw.z = cvt_pk_bf16(st[kt][o+4], st[kt][o+5]);
      pw.w = cvt_pk_bf16(st[kt][o+6], st[kt][o+7]);
      union { uint4v u; short8 s; } pc; pc.u = pw;
      ctx[0] = MFMA32x32(pc.s, v0, ctx[0]);
      ctx[1] = MFMA32x32(pc.s, v1, ctx[1]);
    }
    __builtin_amdgcn_s_setprio(0);
  };

  stage(0, 0);
  __syncthreads();
#pragma unroll 2
  for (int kb=0; kb<8; kb++){
    int cur = kb & 1;
    if (kb < 7) stage(cur^1, kb+1);
    compute(cur, 0);
    compute(cur, 1);
    __syncthreads();
  }

  float zacc = zaccA + zaccB;
  zacc += __shfl_xor(zacc, 32);

  size_t pb = ((size_t)((ksp*8+b)*8+h))*256;
#pragma unroll
  for (int dt=0;dt<2;dt++)
#pragma unroll
    for (int r=0;r<16;r++){
      int trow = 32*w + ((r&3) + 8*(r>>2) + 4*hl);
      partb[(pb + trow)*64 + dt*32 + lq] = bf16_1(ctx[dt][r]);
    }
  if (l < 32) zpart[pb + 32*w + l] = zacc;
}

// ---------------------------------------------------------------- K4a: merge 8 k-split bf16 partials -> ctx bf16
__global__ __launch_bounds__(256) void lt_mergepart(const unsigned short* __restrict__ partb,
                                                    const float* __restrict__ zpart,
                                                    unsigned short* __restrict__ ctxbf){
  __shared__ float zl[64];
  int bid = blockIdx.x; int tid = threadIdx.x;
  int b = bid >> 5, h = (bid>>2)&7, tq = bid & 3;
  int tloc = tid >> 2, dq = tid & 3;
  int t = tq*64 + tloc;

  if (tid < 64){
    float z = 0.0f;
#pragma unroll
    for (int kse=0;kse<8;kse++)
      z += zpart[((size_t)((kse*8+b)*8+h))*256 + tq*64 + tid];
    zl[tid] = z;
  }
  __syncthreads();

  float s[16];
#pragma unroll
  for (int j=0;j<16;j++) s[j] = 0.0f;
#pragma unroll
  for (int kse=0;kse<8;kse++){
    const unsigned short* p = partb + (((size_t)((kse*8+b)*8+h))*256 + t)*64 + dq*16;
    short8 u0 = *(const short8*)(p);
    short8 u1 = *(const short8*)(p + 8);
#pragma unroll
    for (int j=0;j<8;j++){
      s[j]   += bf2f((unsigned short)u0[j]);
      s[j+8] += bf2f((unsigned short)u1[j]);
    }
  }
  float rz = 1.0f / zl[tloc];
  uint4v o0, o1;
  o0.x = cvt_pk_bf16(s[0]*rz,  s[1]*rz);  o0.y = cvt_pk_bf16(s[2]*rz,  s[3]*rz);
  o0.z = cvt_pk_bf16(s[4]*rz,  s[5]*rz);  o0.w = cvt_pk_bf16(s[6]*rz,  s[7]*rz);
  o1.x = cvt_pk_bf16(s[8]*rz,  s[9]*rz);  o1.y = cvt_pk_bf16(s[10]*rz, s[11]*rz);
  o1.z = cvt_pk_bf16(s[12]*rz, s[13]*rz); o1.w = cvt_pk_bf16(s[14]*rz, s[15]*rz);
  unsigned short* dst = ctxbf + (size_t)(b*256 + t)*512 + h*64 + dq*16;
  *(uint4v*)(dst)     = o0;
  *(uint4v*)(dst + 8) = o1;
}

// ---------------------------------------------------------------- K4b: out-proj GEMM (64 blocks) -> ybf
__global__ __launch_bounds__(512, 4) void lt_gemm_out(const unsigned short* __restrict__ ctxbf,
                                                      const unsigned short* __restrict__ woutbf,
                                                      unsigned short* __restrict__ ybf){
  __shared__ char smem[65536];
  int bid = blockIdx.x;
  int m0 = bid >> 2, n0 = bid & 3;
  int tid = threadIdx.x; int l = tid & 63; int w = tid >> 6;
  int wm = w >> 2, wn = w & 3;
  int l15 = l & 15, l4 = l >> 4;

  f32x4 acc[4][2];
  gemm128_body(ctxbf + (size_t)m0*128*512, woutbf + (size_t)n0*128*512, smem, tid, acc);

  int fl = wn*32 + l15;
  unsigned short* LK = (unsigned short*)smem;
#pragma unroll
  for (int mi=0;mi<4;mi++)
#pragma unroll
    for (int ni=0;ni<2;ni++)
#pragma unroll
      for (int r=0;r<4;r++){
        int row = wm*64 + mi*16 + l4*4 + r;
        int f = fl + ni*16;
        LK[row*136 + f] = bf16_1(acc[mi][ni][r]);
      }
  __syncthreads();
  size_t gbase = (size_t)m0*128*512 + n0*128;
#pragma unroll
  for (int it=0; it<4; it++){
    int ci = it*512 + tid; int row = ci>>4, c = ci&15;
    uint4v d = *(const uint4v*)(LK + row*136 + c*8);
    *(uint4v*)(ybf + gbase + (size_t)row*512 + c*8) = d;
  }
}

// ---------------------------------------------------------------- K4c: residual + bias + LayerNorm
__global__ __launch_bounds__(512) void lt_ln(const unsigned short* __restrict__ ybf,
                                             const float* __restrict__ qtok,
                                             const float* __restrict__ bout,
                                             const float* __restrict__ gamma,
                                             const float* __restrict__ beta,
                                             float* __restrict__ out){
  int tid = threadIdx.x; int l = tid & 63; int w = tid >> 6;
  int t = blockIdx.x*8 + w;
  int tok = t & 255;
  int c0 = l*8;

  short8 yb = *(const short8*)(ybf + (size_t)t*512 + c0);
  f32x4 q0 = *(const f32x4*)(qtok + (size_t)tok*512 + c0);
  f32x4 q1 = *(const f32x4*)(qtok + (size_t)tok*512 + c0 + 4);
  f32x4 b0 = *(const f32x4*)(bout + c0);
  f32x4 b1 = *(const f32x4*)(bout + c0 + 4);

  float y[8];
#pragma unroll
  for (int j=0;j<8;j++) y[j] = bf2f((unsigned short)yb[j]);
  y[0]+=q0.x+b0.x; y[1]+=q0.y+b0.y; y[2]+=q0.z+b0.z; y[3]+=q0.w+b0.w;
  y[4]+=q1.x+b1.x; y[5]+=q1.y+b1.y; y[6]+=q1.z+b1.z; y[7]+=q1.w+b1.w;

  float s1 = 0.0f, s2 = 0.0f;
#pragma unroll
  for (int j=0;j<8;j++){ s1 += y[j]; s2 += y[j]*y[j]; }
#pragma unroll
  for (int off=1; off<64; off<<=1){ s1 += __shfl_xor(s1, off); s2 += __shfl_xor(s2, off); }
  float mu = s1 * (1.0f/512.0f);
  float var = s2 * (1.0f/512.0f) - mu*mu;
  float rs = rsqrtf(var + 1e-5f);

  f32x4 g0 = *(const f32x4*)(gamma + c0);
  f32x4 g1 = *(const f32x4*)(gamma + c0 + 4);
  f32x4 e0 = *(const f32x4*)(beta + c0);
  f32x4 e1 = *(const f32x4*)(beta + c0 + 4);
  f32x4 o0, o1;
  o0.x = (y[0]-mu)*rs*g0.x + e0.x; o0.y = (y[1]-mu)*rs*g0.y + e0.y;
  o0.z = (y[2]-mu)*rs*g0.z + e0.z; o0.w = (y[3]-mu)*rs*g0.w + e0.w;
  o1.x = (y[4]-mu)*rs*g1.x + e1.x; o1.y = (y[5]-mu)*rs*g1.y + e1.y;
  o1.z = (y[6]-mu)*rs*g1.z + e1.z; o1.w = (y[7]-mu)*rs*g1.w + e1.w;
  *(f32x4*)(out + (size_t)t*512 + c0)     = o0;
  *(f32x4*)(out + (size_t)t*512 + c0 + 4) = o1;
}

// ----------------------------------------------------------------
extern "C" void kernel_launch(void* const* d_in, const int* in_sizes, int n_in,
                              void* d_out, int out_size, void* d_ws, size_t ws_size,
                              hipStream_t stream){
  (void)in_sizes; (void)n_in; (void)out_size; (void)ws_size;
  const float* x     = (const float*)d_in[0];
  const float* qtok  = (const float*)d_in[1];
  const float* inW   = (const float*)d_in[2];
  const float* inB   = (const float*)d_in[3];
  const float* outW  = (const float*)d_in[4];
  const float* outB  = (const float*)d_in[5];
  const float* gamma = (const float*)d_in[6];
  const float* beta  = (const float*)d_in[7];

  char* ws = (char*)d_ws;
  // kbuf: 64MB head-major K. wq/qt alias its head but are fully consumed by
  // lt_gemm_q BEFORE lt_gemm_kv launches (cross-launch dead -> safe).
  // wkvbf must NOT alias kbuf (R12 race lesson).
  unsigned short* kbuf   = (unsigned short*)(ws);                 // 64 MB
  unsigned short* wqbf   = (unsigned short*)(ws);                 // 512 KB alias kbuf
  unsigned short* qtbf   = (unsigned short*)(ws + 524288);        // 256 KB alias kbuf
  unsigned short* vtbuf  = (unsigned short*)(ws + 67108864);      // 64 MB
  unsigned short* qbuf   = (unsigned short*)(ws + 134217728);     // 256 KB
  unsigned short* wkvbf  = (unsigned short*)(ws + 134479872);     // 1 MB standalone
  unsigned short* xbf    = (unsigned short*)(ws + 135528448);     // 64 MB (dead after gemm_kv)
  unsigned short* partb  = (unsigned short*)(ws + 135528448);     // 16 MB (alias xbf)
  float*          zpart  = (float*)(ws + 169082880);              // 512 KB (inside dead xbf)
  unsigned short* ctxbf  = (unsigned short*)(ws + 169607168);     // 2 MB (inside dead xbf)
  unsigned short* ybf    = (unsigned short*)(ws + 171704320);     // 2 MB (inside dead xbf)
  unsigned short* woutbf = (unsigned short*)(ws + 173801472);     // 512 KB (inside dead xbf; written after gemm_kv)

  lt_conv     <<<dim3(16384), dim3(256), 0, stream>>>(x, xbf);
  lt_conv     <<<dim3(128),   dim3(256), 0, stream>>>(inW, wqbf);
  lt_conv     <<<dim3(256),   dim3(256), 0, stream>>>(inW + 262144, wkvbf);
  lt_conv     <<<dim3(64),    dim3(256), 0, stream>>>(qtok, qtbf);
  lt_gemm_q   <<<dim3(8),     dim3(512), 0, stream>>>(qtbf, wqbf, inB, qbuf);
  lt_gemm_kv  <<<dim3(4096),  dim3(512), 0, stream>>>(xbf, wkvbf, inB, kbuf, vtbuf);
  lt_conv     <<<dim3(128),   dim3(256), 0, stream>>>(outW, woutbf);
  lt_attn     <<<dim3(512),   dim3(512), 0, stream>>>(kbuf, vtbuf, qbuf, partb, zpart);
  lt_mergepart<<<dim3(256),   dim3(256), 0, stream>>>(partb, zpart, ctxbf);
  lt_gemm_out <<<dim3(64),    dim3(512), 0, stream>>>(ctxbf, woutbf, ybf);
  lt_ln       <<<dim3(256),   dim3(512), 0, stream>>>(ybf, qtok, outB, gamma, beta, (float*)d_out);
}